// Round 1
// baseline (253.711 us; speedup 1.0000x reference)
//
#include <hip/hip_runtime.h>
#include <math.h>

#define B_ 4096
#define D_ 784
#define C_ 10
#define E_ 1024
#define K_ 8
#define D4 196   // 784/4 float4 chunks per row

__device__ __forceinline__ float wave_reduce_sum(float v) {
  #pragma unroll
  for (int off = 32; off > 0; off >>= 1)
    v += __shfl_xor(v, off, 64);
  return v;
}

// ---------------- row 1/max(||x||,eps) ----------------
__global__ __launch_bounds__(256) void norm_kernel(const float* __restrict__ x,
                                                   float* __restrict__ rnorm) {
  int lane = threadIdx.x & 63;
  int row  = (blockIdx.x << 2) + (threadIdx.x >> 6);
  const float4* xr = (const float4*)(x + (size_t)row * D_);
  float s = 0.f;
  #pragma unroll
  for (int i = 0; i < 3; ++i) {
    float4 v = xr[i * 64 + lane];
    s += v.x * v.x + v.y * v.y + v.z * v.z + v.w * v.w;
  }
  if (lane < 4) {
    float4 v = xr[192 + lane];
    s += v.x * v.x + v.y * v.y + v.z * v.z + v.w * v.w;
  }
  s = wave_reduce_sum(s);
  if (lane == 0) rnorm[row] = 1.0f / fmaxf(sqrtf(s), 1e-12f);
}

// ---------------- cos = (x * rnorm) @ keys^T : [4096,784]x[1024,784]^T ----------------
// 64x64 tile, BK=16, 256 threads, 4x4 micro-tile with stride-16 columns.
#define BK 16
#define LDR 20  // padded row stride (floats), 16B-aligned, bank-friendly
__global__ __launch_bounds__(256) void gemm_cos(const float* __restrict__ x,
                                                const float* __restrict__ keys,
                                                const float* __restrict__ rnorm,
                                                float* __restrict__ cosb) {
  __shared__ float As[64][LDR];
  __shared__ float Bs[64][LDR];
  int tid = threadIdx.x;
  int tx = tid & 15, ty = tid >> 4;
  int row0 = blockIdx.y * 64, col0 = blockIdx.x * 64;
  float acc[4][4];
  #pragma unroll
  for (int i = 0; i < 4; ++i)
    #pragma unroll
    for (int j = 0; j < 4; ++j) acc[i][j] = 0.f;

  int lr = tid >> 2;            // 0..63
  int lc = (tid & 3) * 4;       // 0,4,8,12
  for (int k0 = 0; k0 < D_; k0 += BK) {
    float4 va = *(const float4*)(x    + (size_t)(row0 + lr) * D_ + k0 + lc);
    float4 vb = *(const float4*)(keys + (size_t)(col0 + lr) * D_ + k0 + lc);
    *(float4*)&As[lr][lc] = va;
    *(float4*)&Bs[lr][lc] = vb;
    __syncthreads();
    #pragma unroll
    for (int kk = 0; kk < BK; kk += 4) {
      float4 a4[4], b4[4];
      #pragma unroll
      for (int i = 0; i < 4; ++i) a4[i] = *(const float4*)&As[ty * 4 + i][kk];
      #pragma unroll
      for (int j = 0; j < 4; ++j) b4[j] = *(const float4*)&Bs[tx + j * 16][kk];
      #pragma unroll
      for (int i = 0; i < 4; ++i)
        #pragma unroll
        for (int j = 0; j < 4; ++j) {
          acc[i][j] = fmaf(a4[i].x, b4[j].x, acc[i][j]);
          acc[i][j] = fmaf(a4[i].y, b4[j].y, acc[i][j]);
          acc[i][j] = fmaf(a4[i].z, b4[j].z, acc[i][j]);
          acc[i][j] = fmaf(a4[i].w, b4[j].w, acc[i][j]);
        }
    }
    __syncthreads();
  }
  #pragma unroll
  for (int i = 0; i < 4; ++i) {
    int r = row0 + ty * 4 + i;
    float rn = rnorm[r];
    #pragma unroll
    for (int j = 0; j < 4; ++j)
      cosb[(size_t)r * E_ + col0 + tx + j * 16] = acc[i][j] * rn;
  }
}

// ---------------- top-8 per row + sorted gather indices ----------------
__global__ __launch_bounds__(256) void topk_kernel(const float* __restrict__ cosb,
                                                   float* __restrict__ sims,
                                                   int* __restrict__ gidx,
                                                   float* __restrict__ wsum) {
  int lane = threadIdx.x & 63;
  int row  = (blockIdx.x << 2) + (threadIdx.x >> 6);
  const float* cr = cosb + (size_t)row * E_;
  float vals[16];
  #pragma unroll
  for (int j = 0; j < 16; ++j) vals[j] = cr[j * 64 + lane];

  float sv[K_]; int si[K_];
  #pragma unroll
  for (int r = 0; r < K_; ++r) {
    float bv = -__builtin_inff(); int bi = 0x7fffffff;
    #pragma unroll
    for (int j = 0; j < 16; ++j) {
      int idx = j * 64 + lane;
      if (vals[j] > bv) { bv = vals[j]; bi = idx; }
    }
    #pragma unroll
    for (int off = 32; off > 0; off >>= 1) {
      float ov = __shfl_xor(bv, off, 64);
      int   oi = __shfl_xor(bi, off, 64);
      if (ov > bv || (ov == bv && oi < bi)) { bv = ov; bi = oi; }
    }
    sv[r] = bv; si[r] = bi;
    // invalidate winner without dynamic register indexing (rule #20)
    #pragma unroll
    for (int j = 0; j < 16; ++j)
      if (j * 64 + lane == bi) vals[j] = -__builtin_inff();
  }

  if (lane == 0) {
    float ws = 0.f;
    #pragma unroll
    for (int r = 0; r < K_; ++r) { sims[row * K_ + r] = sv[r]; ws += sv[r]; }
    wsum[row] = ws;
    // Batcher odd-even sort-8, ascending (static indices)
    #define CSWAP(a, b) { int lo = si[a] < si[b] ? si[a] : si[b]; \
                          int hi = si[a] < si[b] ? si[b] : si[a]; \
                          si[a] = lo; si[b] = hi; }
    CSWAP(0,1) CSWAP(2,3) CSWAP(4,5) CSWAP(6,7)
    CSWAP(0,2) CSWAP(1,3) CSWAP(4,6) CSWAP(5,7)
    CSWAP(1,2) CSWAP(5,6)
    CSWAP(0,4) CSWAP(1,5) CSWAP(2,6) CSWAP(3,7)
    CSWAP(2,4) CSWAP(3,5)
    CSWAP(1,2) CSWAP(3,4) CSWAP(5,6)
    #undef CSWAP
    #pragma unroll
    for (int r = 0; r < K_; ++r) gidx[row * K_ + r] = si[r];
  }
}

// ---------------- ensemble: wave per sample ----------------
__global__ __launch_bounds__(256) void ensemble_kernel(const float* __restrict__ x,
                                                       const float* __restrict__ Wm,
                                                       const float* __restrict__ bm,
                                                       const float* __restrict__ sims,
                                                       const int* __restrict__ gidx,
                                                       const float* __restrict__ wsum,
                                                       float* __restrict__ out) {
  int lane = threadIdx.x & 63;
  int b    = (blockIdx.x << 2) + (threadIdx.x >> 6);
  const float4* xr4 = (const float4*)(x + (size_t)b * D_);
  float4 xr[4];
  #pragma unroll
  for (int i = 0; i < 3; ++i) xr[i] = xr4[i * 64 + lane];
  xr[3] = make_float4(0.f, 0.f, 0.f, 0.f);
  if (lane < 4) xr[3] = xr4[192 + lane];

  float ens[C_];
  #pragma unroll
  for (int c = 0; c < C_; ++c) ens[c] = 0.f;

  for (int k = 0; k < K_; ++k) {
    int   e = gidx[b * K_ + k];
    float w = sims[b * K_ + k];
    const float4* Wr  = (const float4*)(Wm + (size_t)e * (C_ * D_));
    const float*  bmr = bm + e * C_;
    #pragma unroll
    for (int c = 0; c < C_; ++c) {
      const float4* wc = Wr + c * D4;
      float s = 0.f;
      #pragma unroll
      for (int i = 0; i < 3; ++i) {
        float4 wv = wc[i * 64 + lane];
        s += xr[i].x * wv.x + xr[i].y * wv.y + xr[i].z * wv.z + xr[i].w * wv.w;
      }
      if (lane < 4) {
        float4 wv = wc[192 + lane];
        s += xr[3].x * wv.x + xr[3].y * wv.y + xr[3].z * wv.z + xr[3].w * wv.w;
      }
      s = wave_reduce_sum(s);
      float val = tanhf((s + bmr[c]) * 0.1f) * 10.0f;
      ens[c] += val * w;
    }
  }
  if (lane == 0) {
    float ws = wsum[b];
    #pragma unroll
    for (int c = 0; c < C_; ++c) out[(size_t)b * C_ + c] = ens[c] / ws;
  }
}

// ---------------- vanilla log_softmax + tanh head: wave per sample ----------------
__global__ __launch_bounds__(256) void heads_kernel(const float* __restrict__ x,
                                                    const float* __restrict__ Wv,
                                                    const float* __restrict__ bv,
                                                    const float* __restrict__ Wt,
                                                    const float* __restrict__ bt,
                                                    float* __restrict__ out_tanh,
                                                    float* __restrict__ out_van) {
  int lane = threadIdx.x & 63;
  int b    = (blockIdx.x << 2) + (threadIdx.x >> 6);
  const float4* xr4 = (const float4*)(x + (size_t)b * D_);
  float4 xr[4];
  #pragma unroll
  for (int i = 0; i < 3; ++i) xr[i] = xr4[i * 64 + lane];
  xr[3] = make_float4(0.f, 0.f, 0.f, 0.f);
  if (lane < 4) xr[3] = xr4[192 + lane];

  float v[C_], t[C_];
  #pragma unroll
  for (int c = 0; c < C_; ++c) {
    const float4* wv4 = (const float4*)(Wv + (size_t)c * D_);
    const float4* wt4 = (const float4*)(Wt + (size_t)c * D_);
    float sv_ = 0.f, st_ = 0.f;
    #pragma unroll
    for (int i = 0; i < 3; ++i) {
      float4 a = wv4[i * 64 + lane];
      float4 bq = wt4[i * 64 + lane];
      sv_ += xr[i].x * a.x + xr[i].y * a.y + xr[i].z * a.z + xr[i].w * a.w;
      st_ += xr[i].x * bq.x + xr[i].y * bq.y + xr[i].z * bq.z + xr[i].w * bq.w;
    }
    if (lane < 4) {
      float4 a = wv4[192 + lane];
      float4 bq = wt4[192 + lane];
      sv_ += xr[3].x * a.x + xr[3].y * a.y + xr[3].z * a.z + xr[3].w * a.w;
      st_ += xr[3].x * bq.x + xr[3].y * bq.y + xr[3].z * bq.z + xr[3].w * bq.w;
    }
    v[c] = wave_reduce_sum(sv_) + bv[c];
    t[c] = wave_reduce_sum(st_) + bt[c];
  }
  // log_softmax over v (all lanes redundantly)
  float m = v[0];
  #pragma unroll
  for (int c = 1; c < C_; ++c) m = fmaxf(m, v[c]);
  float se = 0.f;
  #pragma unroll
  for (int c = 0; c < C_; ++c) se += expf(v[c] - m);
  float lse = m + logf(se);
  if (lane == 0) {
    #pragma unroll
    for (int c = 0; c < C_; ++c) {
      out_van[(size_t)b * C_ + c]  = v[c] - lse;
      out_tanh[(size_t)b * C_ + c] = tanhf(t[c] * 0.1f) * 10.0f;
    }
  }
}

extern "C" void kernel_launch(void* const* d_in, const int* in_sizes, int n_in,
                              void* d_out, int out_size, void* d_ws, size_t ws_size,
                              hipStream_t stream) {
  const float* x    = (const float*)d_in[0];
  const float* keys = (const float*)d_in[1];
  const float* Wm   = (const float*)d_in[2];
  const float* bm   = (const float*)d_in[3];
  const float* Wv   = (const float*)d_in[4];
  const float* bv   = (const float*)d_in[5];
  const float* Wt   = (const float*)d_in[6];
  const float* bt   = (const float*)d_in[7];
  float* out = (float*)d_out;

  float* rnorm = (float*)d_ws;                       // B_
  float* cosb  = rnorm + B_;                         // B_*E_
  float* sims  = cosb + (size_t)B_ * E_;             // B_*K_
  float* wsumb = sims + B_ * K_;                     // B_
  int*   gidx  = (int*)(wsumb + B_);                 // B_*K_

  norm_kernel<<<B_ / 4, 256, 0, stream>>>(x, rnorm);
  dim3 g(E_ / 64, B_ / 64);
  gemm_cos<<<g, 256, 0, stream>>>(x, keys, rnorm, cosb);
  topk_kernel<<<B_ / 4, 256, 0, stream>>>(cosb, sims, gidx, wsumb);
  ensemble_kernel<<<B_ / 4, 256, 0, stream>>>(x, Wm, bm, sims, gidx, wsumb, out);
  heads_kernel<<<B_ / 4, 256, 0, stream>>>(x, Wv, bv, Wt, bt,
                                           out + (size_t)B_ * C_,
                                           out + 2 * (size_t)B_ * C_);
}

// Round 2
// 187.369 us; speedup vs baseline: 1.3541x; 1.3541x over previous
//
#include <hip/hip_runtime.h>
#include <hip/hip_bf16.h>
#include <math.h>

#define B_ 4096
#define D_ 784
#define C_ 10
#define E_ 1024
#define K_ 8
#define KP 800      // K padded to multiple of 32 for MFMA
#define NCAND 16

typedef float f32x4 __attribute__((ext_vector_type(4)));
typedef short s16x8 __attribute__((ext_vector_type(8)));

__device__ __forceinline__ float wave_reduce_sum(float v) {
  #pragma unroll
  for (int off = 32; off > 0; off >>= 1) v += __shfl_xor(v, off, 64);
  return v;
}

// ---------------- row 1/max(||x||,eps) ----------------
__global__ __launch_bounds__(256) void norm_kernel(const float* __restrict__ x,
                                                   float* __restrict__ rnorm) {
  int lane = threadIdx.x & 63;
  int row  = (blockIdx.x << 2) + (threadIdx.x >> 6);
  const float4* xr = (const float4*)(x + (size_t)row * D_);
  float s = 0.f;
  #pragma unroll
  for (int i = 0; i < 3; ++i) {
    float4 v = xr[i * 64 + lane];
    s += v.x * v.x + v.y * v.y + v.z * v.z + v.w * v.w;
  }
  if (lane < 4) {
    float4 v = xr[192 + lane];
    s += v.x * v.x + v.y * v.y + v.z * v.z + v.w * v.w;
  }
  s = wave_reduce_sum(s);
  if (lane == 0) rnorm[row] = 1.0f / fmaxf(sqrtf(s), 1e-12f);
}

// ---------------- fp32 -> bf16 with zero-pad to KP; also zeros count ----------------
__global__ __launch_bounds__(256) void prep_bf16(const float* __restrict__ src,
                                                 unsigned short* __restrict__ dst,
                                                 int nrows, int* __restrict__ count) {
  if (count && blockIdx.x == 0) {
    for (int i = threadIdx.x; i < E_; i += 256) count[i] = 0;
  }
  int t   = blockIdx.x * 256 + threadIdx.x;   // one thread per 8-element chunk
  int row = t / (KP / 8);
  int ch  = t % (KP / 8);                     // 0..99; 98,99 are zero-pad
  if (row >= nrows) return;
  unsigned short u[8];
  if (ch < 98) {
    const float* s = src + (size_t)row * D_ + ch * 8;
    #pragma unroll
    for (int i = 0; i < 8; ++i) {
      __hip_bfloat16 h = __float2bfloat16(s[i]);
      u[i] = *(unsigned short*)&h;
    }
  } else {
    #pragma unroll
    for (int i = 0; i < 8; ++i) u[i] = 0;
  }
  *(uint4*)(dst + (size_t)row * KP + ch * 8) = *(uint4*)u;
}

// ---------------- approx cos = bf16(x) @ bf16(keys)^T * rnorm ----------------
// 64x64 tile, 4 waves (2x2), each wave 32x32 = 2x2 mfma_f32_16x16x32_bf16 frags.
// LDS row stride 40 shorts (80 B): rows spread over 8 bank-groups, <=2-way (free).
__global__ __launch_bounds__(256) void gemm_bf16(const unsigned short* __restrict__ xh,
                                                 const unsigned short* __restrict__ kh,
                                                 const float* __restrict__ rnorm,
                                                 float* __restrict__ cosb) {
  __shared__ unsigned short As[64 * 40];
  __shared__ unsigned short Bs[64 * 40];
  const int tid  = threadIdx.x;
  const int row0 = blockIdx.y * 64, col0 = blockIdx.x * 64;
  const int srow = tid >> 2, sch = tid & 3;           // staging: row, 16B chunk
  const int lane = tid & 63, w = tid >> 6;
  const int wr = (w >> 1) * 32, wc = (w & 1) * 32;    // wave tile origin
  const int fr = lane & 15, fg = lane >> 4;           // fragment row/col, k-group

  const unsigned short* gx = xh + (size_t)(row0 + srow) * KP + sch * 8;
  const unsigned short* gk = kh + (size_t)(col0 + srow) * KP + sch * 8;
  unsigned short* sa = As + srow * 40 + sch * 8;
  unsigned short* sb = Bs + srow * 40 + sch * 8;
  const unsigned short* pa0 = As + (wr + fr) * 40 + fg * 8;
  const unsigned short* pb0 = Bs + (wc + fr) * 40 + fg * 8;

  f32x4 acc[2][2] = {};
  for (int k0 = 0; k0 < KP; k0 += 32) {
    uint4 va = *(const uint4*)(gx + k0);
    uint4 vb = *(const uint4*)(gk + k0);
    __syncthreads();
    *(uint4*)sa = va;
    *(uint4*)sb = vb;
    __syncthreads();
    s16x8 a0 = *(const s16x8*)(pa0);
    s16x8 a1 = *(const s16x8*)(pa0 + 16 * 40);
    s16x8 b0 = *(const s16x8*)(pb0);
    s16x8 b1 = *(const s16x8*)(pb0 + 16 * 40);
    acc[0][0] = __builtin_amdgcn_mfma_f32_16x16x32_bf16(a0, b0, acc[0][0], 0, 0, 0);
    acc[0][1] = __builtin_amdgcn_mfma_f32_16x16x32_bf16(a0, b1, acc[0][1], 0, 0, 0);
    acc[1][0] = __builtin_amdgcn_mfma_f32_16x16x32_bf16(a1, b0, acc[1][0], 0, 0, 0);
    acc[1][1] = __builtin_amdgcn_mfma_f32_16x16x32_bf16(a1, b1, acc[1][1], 0, 0, 0);
  }
  #pragma unroll
  for (int m = 0; m < 2; ++m)
    #pragma unroll
    for (int n = 0; n < 2; ++n)
      #pragma unroll
      for (int j = 0; j < 4; ++j) {
        int r = row0 + wr + m * 16 + fg * 4 + j;      // C/D: row=(lane>>4)*4+reg
        int c = col0 + wc + n * 16 + fr;              //      col=lane&15
        cosb[(size_t)r * E_ + c] = acc[m][n][j] * rnorm[r];
      }
}

// ---------------- approx top-16 -> exact fp32 refine -> exact top-8 ----------------
__global__ __launch_bounds__(256) void topk_refine(const float* __restrict__ cosb,
                                                   const float* __restrict__ x,
                                                   const float* __restrict__ keys,
                                                   const float* __restrict__ rnorm,
                                                   float* __restrict__ sims,
                                                   int* __restrict__ gidx,
                                                   float* __restrict__ wsum,
                                                   int* __restrict__ count) {
  const int lane = threadIdx.x & 63;
  const int row  = (blockIdx.x << 2) + (threadIdx.x >> 6);
  const float* cr = cosb + (size_t)row * E_;
  float vals[16];
  #pragma unroll
  for (int j = 0; j < 16; ++j) vals[j] = cr[j * 64 + lane];

  int cid[NCAND];
  #pragma unroll
  for (int r = 0; r < NCAND; ++r) {
    float bv = -__builtin_inff(); int bi = 0x7fffffff;
    #pragma unroll
    for (int j = 0; j < 16; ++j) {
      int idx = j * 64 + lane;
      if (vals[j] > bv) { bv = vals[j]; bi = idx; }
    }
    #pragma unroll
    for (int off = 32; off > 0; off >>= 1) {
      float ov = __shfl_xor(bv, off, 64);
      int   oi = __shfl_xor(bi, off, 64);
      if (ov > bv || (ov == bv && oi < bi)) { bv = ov; bi = oi; }
    }
    cid[r] = bi;
    #pragma unroll
    for (int j = 0; j < 16; ++j)
      if (j * 64 + lane == bi) vals[j] = -__builtin_inff();
  }

  // exact fp32 cos for candidates
  const float4* xr4 = (const float4*)(x + (size_t)row * D_);
  float4 xr[4];
  #pragma unroll
  for (int i = 0; i < 3; ++i) xr[i] = xr4[i * 64 + lane];
  xr[3] = make_float4(0.f, 0.f, 0.f, 0.f);
  if (lane < 4) xr[3] = xr4[192 + lane];
  float rn = rnorm[row];

  float cv[NCAND];
  #pragma unroll
  for (int j = 0; j < NCAND; ++j) {
    const float4* kr = (const float4*)(keys + (size_t)cid[j] * D_);
    float s = 0.f;
    #pragma unroll
    for (int i = 0; i < 3; ++i) {
      float4 kv = kr[i * 64 + lane];
      s += xr[i].x * kv.x + xr[i].y * kv.y + xr[i].z * kv.z + xr[i].w * kv.w;
    }
    if (lane < 4) {
      float4 kv = kr[192 + lane];
      s += xr[3].x * kv.x + xr[3].y * kv.y + xr[3].z * kv.z + xr[3].w * kv.w;
    }
    cv[j] = wave_reduce_sum(s) * rn;
  }

  // exact top-8 of 16, ties -> lower expert id (all lanes redundantly)
  float sv[K_]; int si[K_];
  #pragma unroll
  for (int r = 0; r < K_; ++r) {
    float bv = -__builtin_inff(); int bid = 0x7fffffff; int bj = -1;
    #pragma unroll
    for (int j = 0; j < NCAND; ++j)
      if (cv[j] > bv || (cv[j] == bv && cid[j] < bid)) { bv = cv[j]; bid = cid[j]; bj = j; }
    sv[r] = bv; si[r] = bid;
    #pragma unroll
    for (int j = 0; j < NCAND; ++j) if (j == bj) cv[j] = -__builtin_inff();
  }

  if (lane == 0) {
    float ws = 0.f;
    #pragma unroll
    for (int r = 0; r < K_; ++r) { sims[row * K_ + r] = sv[r]; ws += sv[r]; }
    wsum[row] = ws;
    #pragma unroll
    for (int r = 0; r < K_; ++r) atomicAdd(&count[si[r]], 1);
    #define CSWAP(a, b) { int lo = si[a] < si[b] ? si[a] : si[b]; \
                          int hi = si[a] < si[b] ? si[b] : si[a]; \
                          si[a] = lo; si[b] = hi; }
    CSWAP(0,1) CSWAP(2,3) CSWAP(4,5) CSWAP(6,7)
    CSWAP(0,2) CSWAP(1,3) CSWAP(4,6) CSWAP(5,7)
    CSWAP(1,2) CSWAP(5,6)
    CSWAP(0,4) CSWAP(1,5) CSWAP(2,6) CSWAP(3,7)
    CSWAP(2,4) CSWAP(3,5)
    CSWAP(1,2) CSWAP(3,4) CSWAP(5,6)
    #undef CSWAP
    #pragma unroll
    for (int r = 0; r < K_; ++r) gidx[row * K_ + r] = si[r];
  }
}

// ---------------- exclusive scan of expert counts (single block) ----------------
__global__ __launch_bounds__(1024) void scan_kernel(const int* __restrict__ count,
                                                    int* __restrict__ offset,
                                                    int* __restrict__ cursor) {
  __shared__ int s[E_];
  int t = threadIdx.x;
  int c = count[t];
  s[t] = c;
  __syncthreads();
  for (int d = 1; d < E_; d <<= 1) {
    int v = (t >= d) ? s[t - d] : 0;
    __syncthreads();
    s[t] += v;
    __syncthreads();
  }
  offset[t] = s[t] - c;
  cursor[t] = s[t] - c;
}

// ---------------- scatter (b,k) pairs into per-expert lists ----------------
__global__ __launch_bounds__(256) void fill_kernel(const int* __restrict__ gidx,
                                                   int* __restrict__ cursor,
                                                   int* __restrict__ list) {
  int t = blockIdx.x * 256 + threadIdx.x;   // one thread per (b,k)
  if (t >= B_ * K_) return;
  int e = gidx[t];
  int p = atomicAdd(&cursor[e], 1);
  list[p] = t;                               // order irrelevant: output slot is t
}

// ---------------- per-expert: stage W_e in LDS, serve assigned samples ----------------
__global__ __launch_bounds__(256) void expert_kernel(const float* __restrict__ x,
                                                     const float* __restrict__ Wm,
                                                     const float* __restrict__ bm,
                                                     const int* __restrict__ list,
                                                     const int* __restrict__ offset,
                                                     const int* __restrict__ count,
                                                     float* __restrict__ slot) {
  __shared__ float Ws[C_ * D_];
  const int e = blockIdx.x;
  const int tid = threadIdx.x;
  const float4* gw = (const float4*)(Wm + (size_t)e * (C_ * D_));
  #pragma unroll
  for (int i = 0; i < 8; ++i) {
    int idx = tid + i * 256;
    if (idx < (C_ * D_) / 4) ((float4*)Ws)[idx] = gw[idx];
  }
  float bmr[C_];
  #pragma unroll
  for (int c = 0; c < C_; ++c) bmr[c] = bm[e * C_ + c];
  __syncthreads();

  const int n = count[e], base = offset[e];
  const int w = tid >> 6, lane = tid & 63;
  for (int s = w; s < n; s += 4) {
    int item = list[base + s];
    int b = item >> 3;
    const float4* xr4 = (const float4*)(x + (size_t)b * D_);
    float4 xr[4];
    #pragma unroll
    for (int i = 0; i < 3; ++i) xr[i] = xr4[i * 64 + lane];
    xr[3] = make_float4(0.f, 0.f, 0.f, 0.f);
    if (lane < 4) xr[3] = xr4[192 + lane];
    #pragma unroll
    for (int c = 0; c < C_; ++c) {
      const float4* wc4 = (const float4*)(Ws + c * D_);
      float sacc = 0.f;
      #pragma unroll
      for (int i = 0; i < 3; ++i) {
        float4 wv = wc4[i * 64 + lane];
        sacc += xr[i].x * wv.x + xr[i].y * wv.y + xr[i].z * wv.z + xr[i].w * wv.w;
      }
      if (lane < 4) {
        float4 wv = wc4[192 + lane];
        sacc += xr[3].x * wv.x + xr[3].y * wv.y + xr[3].z * wv.z + xr[3].w * wv.w;
      }
      sacc = wave_reduce_sum(sacc);
      if (lane == 0) slot[(size_t)item * C_ + c] = tanhf((sacc + bmr[c]) * 0.1f) * 10.0f;
    }
  }
}

// ---------------- weighted reduce of expert outputs ----------------
__global__ __launch_bounds__(256) void reduce_kernel(const float* __restrict__ slot,
                                                     const float* __restrict__ sims,
                                                     const float* __restrict__ wsum,
                                                     float* __restrict__ out) {
  int b = blockIdx.x * 256 + threadIdx.x;
  if (b >= B_) return;
  float ens[C_];
  #pragma unroll
  for (int c = 0; c < C_; ++c) ens[c] = 0.f;
  #pragma unroll
  for (int k = 0; k < K_; ++k) {
    float wv = sims[b * K_ + k];
    const float* sl = slot + (size_t)(b * K_ + k) * C_;
    #pragma unroll
    for (int c = 0; c < C_; ++c) ens[c] += sl[c] * wv;
  }
  float ws = wsum[b];
  #pragma unroll
  for (int c = 0; c < C_; ++c) out[(size_t)b * C_ + c] = ens[c] / ws;
}

// ---------------- vanilla log_softmax + tanh head: wave per sample ----------------
__global__ __launch_bounds__(256) void heads_kernel(const float* __restrict__ x,
                                                    const float* __restrict__ Wv,
                                                    const float* __restrict__ bv,
                                                    const float* __restrict__ Wt,
                                                    const float* __restrict__ bt,
                                                    float* __restrict__ out_tanh,
                                                    float* __restrict__ out_van) {
  int lane = threadIdx.x & 63;
  int b    = (blockIdx.x << 2) + (threadIdx.x >> 6);
  const float4* xr4 = (const float4*)(x + (size_t)b * D_);
  float4 xr[4];
  #pragma unroll
  for (int i = 0; i < 3; ++i) xr[i] = xr4[i * 64 + lane];
  xr[3] = make_float4(0.f, 0.f, 0.f, 0.f);
  if (lane < 4) xr[3] = xr4[192 + lane];

  float v[C_], t[C_];
  #pragma unroll
  for (int c = 0; c < C_; ++c) {
    const float4* wv4 = (const float4*)(Wv + (size_t)c * D_);
    const float4* wt4 = (const float4*)(Wt + (size_t)c * D_);
    float sv_ = 0.f, st_ = 0.f;
    #pragma unroll
    for (int i = 0; i < 3; ++i) {
      float4 a = wv4[i * 64 + lane];
      float4 bq = wt4[i * 64 + lane];
      sv_ += xr[i].x * a.x + xr[i].y * a.y + xr[i].z * a.z + xr[i].w * a.w;
      st_ += xr[i].x * bq.x + xr[i].y * bq.y + xr[i].z * bq.z + xr[i].w * bq.w;
    }
    if (lane < 4) {
      float4 a = wv4[192 + lane];
      float4 bq = wt4[192 + lane];
      sv_ += xr[3].x * a.x + xr[3].y * a.y + xr[3].z * a.z + xr[3].w * a.w;
      st_ += xr[3].x * bq.x + xr[3].y * bq.y + xr[3].z * bq.z + xr[3].w * bq.w;
    }
    v[c] = wave_reduce_sum(sv_) + bv[c];
    t[c] = wave_reduce_sum(st_) + bt[c];
  }
  float m = v[0];
  #pragma unroll
  for (int c = 1; c < C_; ++c) m = fmaxf(m, v[c]);
  float se = 0.f;
  #pragma unroll
  for (int c = 0; c < C_; ++c) se += expf(v[c] - m);
  float lse = m + logf(se);
  if (lane == 0) {
    #pragma unroll
    for (int c = 0; c < C_; ++c) {
      out_van[(size_t)b * C_ + c]  = v[c] - lse;
      out_tanh[(size_t)b * C_ + c] = tanhf(t[c] * 0.1f) * 10.0f;
    }
  }
}

extern "C" void kernel_launch(void* const* d_in, const int* in_sizes, int n_in,
                              void* d_out, int out_size, void* d_ws, size_t ws_size,
                              hipStream_t stream) {
  const float* x    = (const float*)d_in[0];
  const float* keys = (const float*)d_in[1];
  const float* Wm   = (const float*)d_in[2];
  const float* bm   = (const float*)d_in[3];
  const float* Wv   = (const float*)d_in[4];
  const float* bv   = (const float*)d_in[5];
  const float* Wt   = (const float*)d_in[6];
  const float* bt   = (const float*)d_in[7];
  float* out = (float*)d_out;

  char* p = (char*)d_ws;
  auto carve = [&](size_t bytes) { char* q = p; p += (bytes + 255) & ~(size_t)255; return q; };
  float* rnorm = (float*)carve(B_ * 4);
  float* cosb  = (float*)carve((size_t)B_ * E_ * 4);
  float* sims  = (float*)carve(B_ * K_ * 4);
  float* wsumb = (float*)carve(B_ * 4);
  int*   gidx  = (int*)carve(B_ * K_ * 4);
  unsigned short* xh = (unsigned short*)carve((size_t)B_ * KP * 2);
  unsigned short* kh = (unsigned short*)carve((size_t)E_ * KP * 2);
  int*   count  = (int*)carve(E_ * 4);
  int*   offset = (int*)carve(E_ * 4);
  int*   cursor = (int*)carve(E_ * 4);
  int*   list   = (int*)carve(B_ * K_ * 4);
  float* slot   = (float*)carve((size_t)B_ * K_ * C_ * 4);

  norm_kernel<<<B_ / 4, 256, 0, stream>>>(x, rnorm);
  prep_bf16<<<(B_ * (KP / 8) + 255) / 256, 256, 0, stream>>>(x, xh, B_, count);
  prep_bf16<<<(E_ * (KP / 8) + 255) / 256, 256, 0, stream>>>(keys, kh, E_, nullptr);
  dim3 g(E_ / 64, B_ / 64);
  gemm_bf16<<<g, 256, 0, stream>>>(xh, kh, rnorm, cosb);
  topk_refine<<<B_ / 4, 256, 0, stream>>>(cosb, x, keys, rnorm, sims, gidx, wsumb, count);
  scan_kernel<<<1, 1024, 0, stream>>>(count, offset, cursor);
  fill_kernel<<<(B_ * K_ + 255) / 256, 256, 0, stream>>>(gidx, cursor, list);
  expert_kernel<<<E_, 256, 0, stream>>>(x, Wm, bm, list, offset, count, slot);
  reduce_kernel<<<(B_ + 255) / 256, 256, 0, stream>>>(slot, sims, wsumb, out);
  heads_kernel<<<B_ / 4, 256, 0, stream>>>(x, Wv, bv, Wt, bt,
                                           out + (size_t)B_ * C_,
                                           out + 2 * (size_t)B_ * C_);
}

// Round 3
// 119.564 us; speedup vs baseline: 2.1220x; 1.5671x over previous
//
#include <hip/hip_runtime.h>
#include <hip/hip_bf16.h>
#include <math.h>

#define B_ 4096
#define D_ 784
#define C_ 10
#define E_ 1024
#define K_ 8
#define KP 800      // D padded to multiple of 32 for MFMA
#define NCAND 16
#define LDW 808     // LDS row stride (shorts) for W tile in expert_mfma

typedef float f32x4 __attribute__((ext_vector_type(4)));
typedef short s16x8 __attribute__((ext_vector_type(8)));

__device__ __forceinline__ float wave_reduce_sum(float v) {
  #pragma unroll
  for (int off = 32; off > 0; off >>= 1) v += __shfl_xor(v, off, 64);
  return v;
}

// ---------------- fp32 -> bf16 with zero-pad to KP; also zeros count ----------------
__global__ __launch_bounds__(256) void prep_bf16(const float* __restrict__ src,
                                                 unsigned short* __restrict__ dst,
                                                 int nrows, int* __restrict__ count) {
  if (count && blockIdx.x == 0) {
    for (int i = threadIdx.x; i < E_; i += 256) count[i] = 0;
  }
  int t   = blockIdx.x * 256 + threadIdx.x;   // one thread per 8-element chunk
  int row = t / (KP / 8);
  int ch  = t % (KP / 8);                     // 0..99; 98,99 are zero-pad
  if (row >= nrows) return;
  unsigned short u[8];
  if (ch < 98) {
    const float* s = src + (size_t)row * D_ + ch * 8;
    #pragma unroll
    for (int i = 0; i < 8; ++i) {
      __hip_bfloat16 h = __float2bfloat16(s[i]);
      u[i] = *(unsigned short*)&h;
    }
  } else {
    #pragma unroll
    for (int i = 0; i < 8; ++i) u[i] = 0;
  }
  *(uint4*)(dst + (size_t)row * KP + ch * 8) = *(uint4*)u;
}

// ---------------- approx dot = bf16(x) @ bf16(keys)^T (no rnorm: scale-invariant order) ----
__global__ __launch_bounds__(256) void gemm_bf16(const unsigned short* __restrict__ xh,
                                                 const unsigned short* __restrict__ kh,
                                                 float* __restrict__ cosb) {
  __shared__ unsigned short As[64 * 40];
  __shared__ unsigned short Bs[64 * 40];
  const int tid  = threadIdx.x;
  const int row0 = blockIdx.y * 64, col0 = blockIdx.x * 64;
  const int srow = tid >> 2, sch = tid & 3;
  const int lane = tid & 63, w = tid >> 6;
  const int wr = (w >> 1) * 32, wc = (w & 1) * 32;
  const int fr = lane & 15, fg = lane >> 4;

  const unsigned short* gx = xh + (size_t)(row0 + srow) * KP + sch * 8;
  const unsigned short* gk = kh + (size_t)(col0 + srow) * KP + sch * 8;
  unsigned short* sa = As + srow * 40 + sch * 8;
  unsigned short* sb = Bs + srow * 40 + sch * 8;
  const unsigned short* pa0 = As + (wr + fr) * 40 + fg * 8;
  const unsigned short* pb0 = Bs + (wc + fr) * 40 + fg * 8;

  f32x4 acc[2][2] = {};
  for (int k0 = 0; k0 < KP; k0 += 32) {
    uint4 va = *(const uint4*)(gx + k0);
    uint4 vb = *(const uint4*)(gk + k0);
    __syncthreads();
    *(uint4*)sa = va;
    *(uint4*)sb = vb;
    __syncthreads();
    s16x8 a0 = *(const s16x8*)(pa0);
    s16x8 a1 = *(const s16x8*)(pa0 + 16 * 40);
    s16x8 b0 = *(const s16x8*)(pb0);
    s16x8 b1 = *(const s16x8*)(pb0 + 16 * 40);
    acc[0][0] = __builtin_amdgcn_mfma_f32_16x16x32_bf16(a0, b0, acc[0][0], 0, 0, 0);
    acc[0][1] = __builtin_amdgcn_mfma_f32_16x16x32_bf16(a0, b1, acc[0][1], 0, 0, 0);
    acc[1][0] = __builtin_amdgcn_mfma_f32_16x16x32_bf16(a1, b0, acc[1][0], 0, 0, 0);
    acc[1][1] = __builtin_amdgcn_mfma_f32_16x16x32_bf16(a1, b1, acc[1][1], 0, 0, 0);
  }
  #pragma unroll
  for (int m = 0; m < 2; ++m)
    #pragma unroll
    for (int n = 0; n < 2; ++n)
      #pragma unroll
      for (int j = 0; j < 4; ++j) {
        int r = row0 + wr + m * 16 + fg * 4 + j;
        int c = col0 + wc + n * 16 + fr;
        cosb[(size_t)r * E_ + c] = acc[m][n][j];
      }
}

// ---------------- approx top-16 -> exact fp32 refine -> exact top-8 (rnorm inline) ----------
__global__ __launch_bounds__(256) void topk_refine(const float* __restrict__ cosb,
                                                   const float* __restrict__ x,
                                                   const float* __restrict__ keys,
                                                   float* __restrict__ sims,
                                                   int* __restrict__ gidx,
                                                   float* __restrict__ wsum,
                                                   int* __restrict__ count) {
  const int lane = threadIdx.x & 63;
  const int row  = (blockIdx.x << 2) + (threadIdx.x >> 6);

  // x row in registers + rnorm
  const float4* xr4 = (const float4*)(x + (size_t)row * D_);
  float4 xr[4];
  #pragma unroll
  for (int i = 0; i < 3; ++i) xr[i] = xr4[i * 64 + lane];
  xr[3] = make_float4(0.f, 0.f, 0.f, 0.f);
  if (lane < 4) xr[3] = xr4[192 + lane];
  float n2 = 0.f;
  #pragma unroll
  for (int i = 0; i < 4; ++i)
    n2 += xr[i].x * xr[i].x + xr[i].y * xr[i].y + xr[i].z * xr[i].z + xr[i].w * xr[i].w;
  n2 = wave_reduce_sum(n2);
  const float rn = 1.0f / fmaxf(sqrtf(n2), 1e-12f);

  const float* cr = cosb + (size_t)row * E_;
  float vals[16];
  #pragma unroll
  for (int j = 0; j < 16; ++j) vals[j] = cr[j * 64 + lane];

  int cid[NCAND];
  #pragma unroll
  for (int r = 0; r < NCAND; ++r) {
    float bv = -__builtin_inff(); int bi = 0x7fffffff;
    #pragma unroll
    for (int j = 0; j < 16; ++j) {
      int idx = j * 64 + lane;
      if (vals[j] > bv) { bv = vals[j]; bi = idx; }
    }
    #pragma unroll
    for (int off = 32; off > 0; off >>= 1) {
      float ov = __shfl_xor(bv, off, 64);
      int   oi = __shfl_xor(bi, off, 64);
      if (ov > bv || (ov == bv && oi < bi)) { bv = ov; bi = oi; }
    }
    cid[r] = bi;
    #pragma unroll
    for (int j = 0; j < 16; ++j)
      if (j * 64 + lane == bi) vals[j] = -__builtin_inff();
  }

  float cv[NCAND];
  #pragma unroll
  for (int j = 0; j < NCAND; ++j) {
    const float4* kr = (const float4*)(keys + (size_t)cid[j] * D_);
    float s = 0.f;
    #pragma unroll
    for (int i = 0; i < 3; ++i) {
      float4 kv = kr[i * 64 + lane];
      s += xr[i].x * kv.x + xr[i].y * kv.y + xr[i].z * kv.z + xr[i].w * kv.w;
    }
    if (lane < 4) {
      float4 kv = kr[192 + lane];
      s += xr[3].x * kv.x + xr[3].y * kv.y + xr[3].z * kv.z + xr[3].w * kv.w;
    }
    cv[j] = wave_reduce_sum(s) * rn;
  }

  float sv[K_]; int si[K_];
  #pragma unroll
  for (int r = 0; r < K_; ++r) {
    float bv = -__builtin_inff(); int bid = 0x7fffffff; int bj = -1;
    #pragma unroll
    for (int j = 0; j < NCAND; ++j)
      if (cv[j] > bv || (cv[j] == bv && cid[j] < bid)) { bv = cv[j]; bid = cid[j]; bj = j; }
    sv[r] = bv; si[r] = bid;
    #pragma unroll
    for (int j = 0; j < NCAND; ++j) if (j == bj) cv[j] = -__builtin_inff();
  }

  if (lane == 0) {
    float ws = 0.f;
    #pragma unroll
    for (int r = 0; r < K_; ++r) { sims[row * K_ + r] = sv[r]; ws += sv[r]; }
    wsum[row] = ws;
    #pragma unroll
    for (int r = 0; r < K_; ++r) atomicAdd(&count[si[r]], 1);
    #define CSWAP(a, b) { int lo = si[a] < si[b] ? si[a] : si[b]; \
                          int hi = si[a] < si[b] ? si[b] : si[a]; \
                          si[a] = lo; si[b] = hi; }
    CSWAP(0,1) CSWAP(2,3) CSWAP(4,5) CSWAP(6,7)
    CSWAP(0,2) CSWAP(1,3) CSWAP(4,6) CSWAP(5,7)
    CSWAP(1,2) CSWAP(5,6)
    CSWAP(0,4) CSWAP(1,5) CSWAP(2,6) CSWAP(3,7)
    CSWAP(2,4) CSWAP(3,5)
    CSWAP(1,2) CSWAP(3,4) CSWAP(5,6)
    #undef CSWAP
    #pragma unroll
    for (int r = 0; r < K_; ++r) gidx[row * K_ + r] = si[r];
  }
}

// ---------------- exclusive scan of expert counts (single block) ----------------
__global__ __launch_bounds__(1024) void scan_kernel(const int* __restrict__ count,
                                                    int* __restrict__ offset,
                                                    int* __restrict__ cursor) {
  __shared__ int s[E_];
  int t = threadIdx.x;
  int c = count[t];
  s[t] = c;
  __syncthreads();
  for (int d = 1; d < E_; d <<= 1) {
    int v = (t >= d) ? s[t - d] : 0;
    __syncthreads();
    s[t] += v;
    __syncthreads();
  }
  offset[t] = s[t] - c;
  cursor[t] = s[t] - c;
}

// ---------------- scatter (b,k) pairs into per-expert lists ----------------
__global__ __launch_bounds__(256) void fill_kernel(const int* __restrict__ gidx,
                                                   int* __restrict__ cursor,
                                                   int* __restrict__ list) {
  int t = blockIdx.x * 256 + threadIdx.x;
  if (t >= B_ * K_) return;
  int e = gidx[t];
  int p = atomicAdd(&cursor[e], 1);
  list[p] = t;                               // order irrelevant: output slot is t
}

// ---------------- per-expert bf16 MFMA: X_e[n,784] @ W_e^T -> tanh -> slot ----------------
__global__ __launch_bounds__(256) void expert_mfma(const float* __restrict__ Wm,
                                                   const float* __restrict__ bm,
                                                   const unsigned short* __restrict__ xh,
                                                   const int* __restrict__ list,
                                                   const int* __restrict__ offset,
                                                   const int* __restrict__ count,
                                                   float* __restrict__ slot) {
  __shared__ unsigned short Wl[16 * LDW];   // 16 class rows (10 real) x 800 k (bf16)
  const int e   = blockIdx.x;
  const int tid = threadIdx.x;
  const int n = count[e], base = offset[e];

  // stage W_e fp32 -> bf16 LDS; rows 10..15 and k>=784 are zero
  for (int ch = tid; ch < 1600; ch += 256) {   // 1600 chunks of 8 shorts
    int r  = ch / 100;
    int kc = (ch % 100) * 8;
    unsigned short u[8];
    if (r < 10 && kc < 784) {
      const float* src = Wm + (size_t)e * (C_ * D_) + r * D_ + kc;
      #pragma unroll
      for (int i = 0; i < 8; ++i) {
        __hip_bfloat16 h = __float2bfloat16(src[i]);
        u[i] = *(unsigned short*)&h;
      }
    } else {
      #pragma unroll
      for (int i = 0; i < 8; ++i) u[i] = 0;
    }
    *(uint4*)(Wl + r * LDW + kc) = *(uint4*)u;
  }
  __syncthreads();
  if (n == 0) return;

  const int lane = tid & 63, w = tid >> 6;
  const int fr = lane & 15, fg = lane >> 4;
  const float bias = (fr < C_) ? bm[e * C_ + fr] : 0.f;
  const unsigned short* bp = Wl + fr * LDW + fg * 8;

  for (int c0 = w * 16; c0 < n; c0 += 64) {
    int sidx = c0 + fr;
    int item = (sidx < n) ? list[base + sidx] : list[base];
    const unsigned short* xrow = xh + (size_t)(item >> 3) * KP + fg * 8;
    f32x4 acc = {};
    #pragma unroll
    for (int k0 = 0; k0 < KP; k0 += 32) {
      s16x8 a = *(const s16x8*)(xrow + k0);
      s16x8 b = *(const s16x8*)(bp + k0);
      acc = __builtin_amdgcn_mfma_f32_16x16x32_bf16(a, b, acc, 0, 0, 0);
    }
    if (fr < C_) {
      #pragma unroll
      for (int j = 0; j < 4; ++j) {
        int s2 = c0 + fg * 4 + j;
        if (s2 < n) {
          int it2 = list[base + s2];
          slot[(size_t)it2 * C_ + fr] = tanhf((acc[j] + bias) * 0.1f) * 10.0f;
        }
      }
    }
  }
}

// ---------------- weighted reduce of expert outputs ----------------
__global__ __launch_bounds__(256) void reduce_kernel(const float* __restrict__ slot,
                                                     const float* __restrict__ sims,
                                                     const float* __restrict__ wsum,
                                                     float* __restrict__ out) {
  int b = blockIdx.x * 256 + threadIdx.x;
  if (b >= B_) return;
  float ens[C_];
  #pragma unroll
  for (int c = 0; c < C_; ++c) ens[c] = 0.f;
  #pragma unroll
  for (int k = 0; k < K_; ++k) {
    float wv = sims[b * K_ + k];
    const float* sl = slot + (size_t)(b * K_ + k) * C_;
    #pragma unroll
    for (int c = 0; c < C_; ++c) ens[c] += sl[c] * wv;
  }
  float ws = wsum[b];
  #pragma unroll
  for (int c = 0; c < C_; ++c) out[(size_t)b * C_ + c] = ens[c] / ws;
}

// ---------------- vanilla log_softmax + tanh head: wave per sample ----------------
__global__ __launch_bounds__(256) void heads_kernel(const float* __restrict__ x,
                                                    const float* __restrict__ Wv,
                                                    const float* __restrict__ bv,
                                                    const float* __restrict__ Wt,
                                                    const float* __restrict__ bt,
                                                    float* __restrict__ out_tanh,
                                                    float* __restrict__ out_van) {
  int lane = threadIdx.x & 63;
  int b    = (blockIdx.x << 2) + (threadIdx.x >> 6);
  const float4* xr4 = (const float4*)(x + (size_t)b * D_);
  float4 xr[4];
  #pragma unroll
  for (int i = 0; i < 3; ++i) xr[i] = xr4[i * 64 + lane];
  xr[3] = make_float4(0.f, 0.f, 0.f, 0.f);
  if (lane < 4) xr[3] = xr4[192 + lane];

  float v[C_], t[C_];
  #pragma unroll
  for (int c = 0; c < C_; ++c) {
    const float4* wv4 = (const float4*)(Wv + (size_t)c * D_);
    const float4* wt4 = (const float4*)(Wt + (size_t)c * D_);
    float sv_ = 0.f, st_ = 0.f;
    #pragma unroll
    for (int i = 0; i < 3; ++i) {
      float4 a = wv4[i * 64 + lane];
      float4 bq = wt4[i * 64 + lane];
      sv_ += xr[i].x * a.x + xr[i].y * a.y + xr[i].z * a.z + xr[i].w * a.w;
      st_ += xr[i].x * bq.x + xr[i].y * bq.y + xr[i].z * bq.z + xr[i].w * bq.w;
    }
    if (lane < 4) {
      float4 a = wv4[192 + lane];
      float4 bq = wt4[192 + lane];
      sv_ += xr[3].x * a.x + xr[3].y * a.y + xr[3].z * a.z + xr[3].w * a.w;
      st_ += xr[3].x * bq.x + xr[3].y * bq.y + xr[3].z * bq.z + xr[3].w * bq.w;
    }
    v[c] = wave_reduce_sum(sv_) + bv[c];
    t[c] = wave_reduce_sum(st_) + bt[c];
  }
  float m = v[0];
  #pragma unroll
  for (int c = 1; c < C_; ++c) m = fmaxf(m, v[c]);
  float se = 0.f;
  #pragma unroll
  for (int c = 0; c < C_; ++c) se += expf(v[c] - m);
  float lse = m + logf(se);
  if (lane == 0) {
    #pragma unroll
    for (int c = 0; c < C_; ++c) {
      out_van[(size_t)b * C_ + c]  = v[c] - lse;
      out_tanh[(size_t)b * C_ + c] = tanhf(t[c] * 0.1f) * 10.0f;
    }
  }
}

extern "C" void kernel_launch(void* const* d_in, const int* in_sizes, int n_in,
                              void* d_out, int out_size, void* d_ws, size_t ws_size,
                              hipStream_t stream) {
  const float* x    = (const float*)d_in[0];
  const float* keys = (const float*)d_in[1];
  const float* Wm   = (const float*)d_in[2];
  const float* bm   = (const float*)d_in[3];
  const float* Wv   = (const float*)d_in[4];
  const float* bv   = (const float*)d_in[5];
  const float* Wt   = (const float*)d_in[6];
  const float* bt   = (const float*)d_in[7];
  float* out = (float*)d_out;

  char* p = (char*)d_ws;
  auto carve = [&](size_t bytes) { char* q = p; p += (bytes + 255) & ~(size_t)255; return q; };
  float* cosb  = (float*)carve((size_t)B_ * E_ * 4);
  float* sims  = (float*)carve(B_ * K_ * 4);
  float* wsumb = (float*)carve(B_ * 4);
  int*   gidx  = (int*)carve(B_ * K_ * 4);
  unsigned short* xh = (unsigned short*)carve((size_t)B_ * KP * 2);
  unsigned short* kh = (unsigned short*)carve((size_t)E_ * KP * 2);
  int*   count  = (int*)carve(E_ * 4);
  int*   offset = (int*)carve(E_ * 4);
  int*   cursor = (int*)carve(E_ * 4);
  int*   list   = (int*)carve(B_ * K_ * 4);
  float* slot   = (float*)carve((size_t)B_ * K_ * C_ * 4);

  prep_bf16<<<(B_ * (KP / 8) + 255) / 256, 256, 0, stream>>>(x, xh, B_, count);
  prep_bf16<<<(E_ * (KP / 8) + 255) / 256, 256, 0, stream>>>(keys, kh, E_, nullptr);
  dim3 g(E_ / 64, B_ / 64);
  gemm_bf16<<<g, 256, 0, stream>>>(xh, kh, cosb);
  topk_refine<<<B_ / 4, 256, 0, stream>>>(cosb, x, keys, sims, gidx, wsumb, count);
  scan_kernel<<<1, 1024, 0, stream>>>(count, offset, cursor);
  fill_kernel<<<(B_ * K_ + 255) / 256, 256, 0, stream>>>(gidx, cursor, list);
  expert_mfma<<<E_, 256, 0, stream>>>(Wm, bm, xh, list, offset, count, slot);
  reduce_kernel<<<(B_ + 255) / 256, 256, 0, stream>>>(slot, sims, wsumb, out);
  heads_kernel<<<B_ / 4, 256, 0, stream>>>(x, Wv, bv, Wt, bt,
                                           out + (size_t)B_ * C_,
                                           out + 2 * (size_t)B_ * C_);
}